// Round 1
// baseline (702.957 us; speedup 1.0000x reference)
//
#include <hip/hip_runtime.h>
#include <math.h>

// Problem geometry is fixed by setup_inputs(): B=32, H=512, W=512.
static constexpr int IMG_W   = 512;
static constexpr int LOG2_W  = 9;

// ---------------- union-find primitives (Playne-style BUF) ----------------

__device__ __forceinline__ int find_root(const int* L, int x) {
    int p = L[x];
    while (p != x) { x = p; p = L[x]; }
    return x;
}

__device__ __forceinline__ void merge_labels(int* L, int a, int b) {
    while (true) {
        a = find_root(L, a);
        b = find_root(L, b);
        if (a == b) return;
        if (a < b) { int tmp = a; a = b; b = tmp; }   // a > b
        int old = atomicMin(&L[a], b);
        if (old == a) return;   // successfully linked root a -> b
        a = old;                // displaced value must be re-merged with b
    }
}

// ---------------- kernels ----------------

__global__ void ccl_init(int* __restrict__ L, int* __restrict__ area,
                         double* __restrict__ acc, int N) {
    int i = blockIdx.x * blockDim.x + threadIdx.x;
    if (i < N) { L[i] = i; area[i] = 0; }
    if (i < 4) acc[i] = 0.0;
}

__global__ void ccl_merge(const float* __restrict__ t, int* __restrict__ L, int N) {
    int i = blockIdx.x * blockDim.x + threadIdx.x;
    if (i >= N) return;
    if (t[i] == 0.0f) return;
    int x = i & (IMG_W - 1);
    int y = (i >> LOG2_W) & (IMG_W - 1);   // row within its 512x512 image
    if (x > 0 && t[i - 1]     != 0.0f) merge_labels(L, i, i - 1);
    if (y > 0 && t[i - IMG_W] != 0.0f) merge_labels(L, i, i - IMG_W);
}

__global__ void ccl_flatten_count(const float* __restrict__ t, int* __restrict__ L,
                                  int* __restrict__ area, int N) {
    int i = blockIdx.x * blockDim.x + threadIdx.x;
    if (i >= N) return;
    if (t[i] == 0.0f) return;
    int r = find_root(L, i);
    L[i] = r;                      // path compression (safe: only shortens paths)
    atomicAdd(&area[r], 1);
}

__global__ void bce_reduce(const float* __restrict__ x, const float* __restrict__ t,
                           const int* __restrict__ L, const int* __restrict__ area,
                           double* __restrict__ acc, int N) {
    float s_fg = 0.f;   // sum over fg pixels of bce / (sqrt(area)+1)
    float s_bg = 0.f;   // sum over bg pixels of bce
    float s_sq = 0.f;   // sum over fg pixels of sqrt(area)
    float s_n  = 0.f;   // fg pixel count
    int stride = gridDim.x * blockDim.x;
    for (int i = blockIdx.x * blockDim.x + threadIdx.x; i < N; i += stride) {
        float xi = x[i], ti = t[i];
        float bce = fmaxf(xi, 0.f) - xi * ti + log1pf(expf(-fabsf(xi)));
        if (ti != 0.0f) {
            float w = sqrtf((float)area[L[i]]);
            s_fg += bce / (w + 1.f);
            s_sq += w;
            s_n  += 1.f;
        } else {
            s_bg += bce;
        }
    }
    // wave(64) reduction, then one double atomic per wave per quantity
    for (int o = 32; o > 0; o >>= 1) {
        s_fg += __shfl_down(s_fg, o, 64);
        s_bg += __shfl_down(s_bg, o, 64);
        s_sq += __shfl_down(s_sq, o, 64);
        s_n  += __shfl_down(s_n,  o, 64);
    }
    if ((threadIdx.x & 63) == 0) {
        atomicAdd(&acc[0], (double)s_fg);
        atomicAdd(&acc[1], (double)s_bg);
        atomicAdd(&acc[2], (double)s_sq);
        atomicAdd(&acc[3], (double)s_n);
    }
}

__global__ void finalize(const double* __restrict__ acc, float* __restrict__ out, int N) {
    double mean_nz = acc[2] / fmax(acc[3], 1.0);
    double loss = (acc[0] + acc[1] / (mean_nz + 1.0)) / (double)N;
    out[0] = (float)loss;
}

// ---------------- launch ----------------

extern "C" void kernel_launch(void* const* d_in, const int* in_sizes, int n_in,
                              void* d_out, int out_size, void* d_ws, size_t ws_size,
                              hipStream_t stream) {
    const float* x = (const float*)d_in[0];   // logits
    const float* t = (const float*)d_in[1];   // binary targets
    float* out = (float*)d_out;
    const int N = in_sizes[0];                // B*H*W = 8388608

    // workspace layout: [labels: N int][area: N int][acc: 4 double]
    int* L    = (int*)d_ws;
    int* area = L + N;
    double* acc = (double*)(area + N);

    const int threads = 256;
    const int blocks  = (N + threads - 1) / threads;

    ccl_init<<<blocks, threads, 0, stream>>>(L, area, acc, N);
    ccl_merge<<<blocks, threads, 0, stream>>>(t, L, N);
    ccl_flatten_count<<<blocks, threads, 0, stream>>>(t, L, area, N);
    bce_reduce<<<2048, threads, 0, stream>>>(x, t, L, area, acc, N);
    finalize<<<1, 1, 0, stream>>>(acc, out, N);
}

// Round 2
// 691.523 us; speedup vs baseline: 1.0165x; 1.0165x over previous
//
#include <hip/hip_runtime.h>
#include <math.h>

// Problem geometry is fixed by setup_inputs(): B=32, H=512, W=512.
static constexpr int IMG_W   = 512;
static constexpr int LOG2_W  = 9;

// ---------------- union-find primitives (Playne-style BUF) ----------------

__device__ __forceinline__ int find_root(const int* L, int x) {
    int p = L[x];
    while (p != x) { x = p; p = L[x]; }
    return x;
}

__device__ __forceinline__ void merge_labels(int* L, int a, int b) {
    while (true) {
        a = find_root(L, a);
        b = find_root(L, b);
        if (a == b) return;
        if (a < b) { int tmp = a; a = b; b = tmp; }   // a > b
        int old = atomicMin(&L[a], b);
        if (old == a) return;   // successfully linked root a -> b
        a = old;                // displaced value must be re-merged with b
    }
}

// ---------------- kernels ----------------

__global__ void ccl_init(int4* __restrict__ L4, int4* __restrict__ area4,
                         double* __restrict__ acc, int N4) {
    int i = blockIdx.x * blockDim.x + threadIdx.x;
    if (i < N4) {
        int b = i * 4;
        L4[i]    = make_int4(b, b + 1, b + 2, b + 3);
        area4[i] = make_int4(0, 0, 0, 0);
    }
    if (i < 4) acc[i] = 0.0;
}

__global__ void ccl_merge(const float* __restrict__ t, int* __restrict__ L, int N) {
    int i = blockIdx.x * blockDim.x + threadIdx.x;
    if (i >= N) return;
    if (t[i] == 0.0f) return;
    int x = i & (IMG_W - 1);
    int y = (i >> LOG2_W) & (IMG_W - 1);   // row within its 512x512 image
    if (x > 0 && t[i - 1]     != 0.0f) merge_labels(L, i, i - 1);
    if (y > 0 && t[i - IMG_W] != 0.0f) merge_labels(L, i, i - IMG_W);
}

__global__ void ccl_flatten_count(const float* __restrict__ t, int* __restrict__ L,
                                  int* __restrict__ area, int N) {
    int i = blockIdx.x * blockDim.x + threadIdx.x;
    if (i >= N) return;
    if (t[i] == 0.0f) return;
    int r = find_root(L, i);
    L[i] = r;                      // path compression (safe: only shortens paths)
    atomicAdd(&area[r], 1);
}

// branchless per-element update.
// Invariant: for bg pixel i, L[i] == i and area[i] == 0 (roots are always fg
// indices), so w == 0 there and every term degrades gracefully with t == 0.
__device__ __forceinline__ void elem_update(float x, float t, int l,
                                            const int* __restrict__ area,
                                            float& s_fg, float& s_bg,
                                            float& s_sq, float& s_n) {
    float w   = sqrtf((float)area[l]);
    float bce = fmaxf(x, 0.f) - x * t + log1pf(expf(-fabsf(x)));
    float bt  = t * bce;
    s_fg += bt / (w + 1.f);
    s_bg += bce - bt;
    s_sq += w;
    s_n  += t;
}

// Each thread handles exactly 4 float4 groups (16 elements), fully unrolled,
// so all vector loads + 16 independent area-gathers are in flight at once.
__global__ void bce_reduce(const float4* __restrict__ x4, const float4* __restrict__ t4,
                           const int4* __restrict__ L4, const int* __restrict__ area,
                           double* __restrict__ acc, int N4) {
    float s_fg = 0.f, s_bg = 0.f, s_sq = 0.f, s_n = 0.f;
    int tid    = blockIdx.x * blockDim.x + threadIdx.x;
    int stride = gridDim.x * blockDim.x;
#pragma unroll
    for (int k = 0; k < 4; k++) {
        int i = tid + k * stride;
        if (i < N4) {
            float4 xv = x4[i];
            float4 tv = t4[i];
            int4   lv = L4[i];
            elem_update(xv.x, tv.x, lv.x, area, s_fg, s_bg, s_sq, s_n);
            elem_update(xv.y, tv.y, lv.y, area, s_fg, s_bg, s_sq, s_n);
            elem_update(xv.z, tv.z, lv.z, area, s_fg, s_bg, s_sq, s_n);
            elem_update(xv.w, tv.w, lv.w, area, s_fg, s_bg, s_sq, s_n);
        }
    }
    // wave(64) reduction, then one double atomic per wave per quantity
    for (int o = 32; o > 0; o >>= 1) {
        s_fg += __shfl_down(s_fg, o, 64);
        s_bg += __shfl_down(s_bg, o, 64);
        s_sq += __shfl_down(s_sq, o, 64);
        s_n  += __shfl_down(s_n,  o, 64);
    }
    if ((threadIdx.x & 63) == 0) {
        atomicAdd(&acc[0], (double)s_fg);
        atomicAdd(&acc[1], (double)s_bg);
        atomicAdd(&acc[2], (double)s_sq);
        atomicAdd(&acc[3], (double)s_n);
    }
}

__global__ void finalize(const double* __restrict__ acc, float* __restrict__ out, int N) {
    double mean_nz = acc[2] / fmax(acc[3], 1.0);
    double loss = (acc[0] + acc[1] / (mean_nz + 1.0)) / (double)N;
    out[0] = (float)loss;
}

// ---------------- launch ----------------

extern "C" void kernel_launch(void* const* d_in, const int* in_sizes, int n_in,
                              void* d_out, int out_size, void* d_ws, size_t ws_size,
                              hipStream_t stream) {
    const float* x = (const float*)d_in[0];   // logits
    const float* t = (const float*)d_in[1];   // binary targets
    float* out = (float*)d_out;
    const int N = in_sizes[0];                // B*H*W = 8388608

    // workspace layout: [labels: N int][area: N int][acc: 4 double]
    int* L    = (int*)d_ws;
    int* area = L + N;
    double* acc = (double*)(area + N);

    const int threads = 256;
    const int blocks  = (N + threads - 1) / threads;

    const int N4 = N / 4;                       // N is a multiple of 16
    const int init_blocks = (N4 + threads - 1) / threads;
    ccl_init<<<init_blocks, threads, 0, stream>>>((int4*)L, (int4*)area, acc, N4);
    ccl_merge<<<blocks, threads, 0, stream>>>(t, L, N);
    ccl_flatten_count<<<blocks, threads, 0, stream>>>(t, L, area, N);
    // each thread: 4 unrolled float4 iterations -> 16 elements
    const int red_threads_total = (N4 + 3) / 4;
    const int red_blocks = (red_threads_total + threads - 1) / threads;
    bce_reduce<<<red_blocks, threads, 0, stream>>>((const float4*)x, (const float4*)t,
                                                   (const int4*)L, area, acc, N4);
    finalize<<<1, 1, 0, stream>>>(acc, out, N);
}

// Round 3
// 327.694 us; speedup vs baseline: 2.1452x; 2.1103x over previous
//
#include <hip/hip_runtime.h>
#include <math.h>

// Problem geometry is fixed by setup_inputs(): B=32, H=512, W=512.
static constexpr int IMG_W   = 512;
static constexpr int LOG2_W  = 9;
static constexpr int RED_BLOCKS = 2048;   // bce_reduce grid size (fixed)

// ---------------- union-find primitives (Playne-style BUF) ----------------

__device__ __forceinline__ int find_root(const int* L, int x) {
    int p = L[x];
    while (p != x) { x = p; p = L[x]; }
    return x;
}

__device__ __forceinline__ void merge_labels(int* L, int a, int b) {
    while (true) {
        a = find_root(L, a);
        b = find_root(L, b);
        if (a == b) return;
        if (a < b) { int tmp = a; a = b; b = tmp; }   // a > b
        int old = atomicMin(&L[a], b);
        if (old == a) return;   // successfully linked root a -> b
        a = old;                // displaced value must be re-merged with b
    }
}

// ---------------- kernels ----------------

__global__ void ccl_init(int4* __restrict__ L4, int4* __restrict__ area4, int N4) {
    int i = blockIdx.x * blockDim.x + threadIdx.x;
    if (i < N4) {
        int b = i * 4;
        L4[i]    = make_int4(b, b + 1, b + 2, b + 3);
        area4[i] = make_int4(0, 0, 0, 0);
    }
}

__global__ void ccl_merge(const float* __restrict__ t, int* __restrict__ L, int N) {
    int i = blockIdx.x * blockDim.x + threadIdx.x;
    if (i >= N) return;
    if (t[i] == 0.0f) return;
    int x = i & (IMG_W - 1);
    int y = (i >> LOG2_W) & (IMG_W - 1);   // row within its 512x512 image
    if (x > 0 && t[i - 1]     != 0.0f) merge_labels(L, i, i - 1);
    if (y > 0 && t[i - IMG_W] != 0.0f) merge_labels(L, i, i - IMG_W);
}

__global__ void ccl_flatten_count(const float* __restrict__ t, int* __restrict__ L,
                                  int* __restrict__ area, int N) {
    int i = blockIdx.x * blockDim.x + threadIdx.x;
    if (i >= N) return;
    if (t[i] == 0.0f) return;
    int r = find_root(L, i);
    L[i] = r;                      // path compression (safe: only shortens paths)
    atomicAdd(&area[r], 1);
}

// branchless per-element update.
// Invariant: for bg pixel i, L[i] == i and area[i] == 0 (roots are always fg
// indices), so w == 0 there and every term degrades gracefully with t == 0.
__device__ __forceinline__ void elem_update(float x, float t, int l,
                                            const int* __restrict__ area,
                                            float& s_fg, float& s_bg,
                                            float& s_sq, float& s_n) {
    float w   = sqrtf((float)area[l]);
    float bce = fmaxf(x, 0.f) - x * t + log1pf(expf(-fabsf(x)));
    float bt  = t * bce;
    s_fg += bt / (w + 1.f);
    s_bg += bce - bt;
    s_sq += w;
    s_n  += t;
}

// Each thread handles 4 float4 groups (16 elements), fully unrolled.
// NO global atomics: per-block double4 partial written to `part`.
__global__ void bce_reduce(const float4* __restrict__ x4, const float4* __restrict__ t4,
                           const int4* __restrict__ L4, const int* __restrict__ area,
                           double4* __restrict__ part, int N4) {
    float s_fg = 0.f, s_bg = 0.f, s_sq = 0.f, s_n = 0.f;
    int tid    = blockIdx.x * blockDim.x + threadIdx.x;
    int stride = gridDim.x * blockDim.x;
#pragma unroll
    for (int k = 0; k < 4; k++) {
        int i = tid + k * stride;
        if (i < N4) {
            float4 xv = x4[i];
            float4 tv = t4[i];
            int4   lv = L4[i];
            elem_update(xv.x, tv.x, lv.x, area, s_fg, s_bg, s_sq, s_n);
            elem_update(xv.y, tv.y, lv.y, area, s_fg, s_bg, s_sq, s_n);
            elem_update(xv.z, tv.z, lv.z, area, s_fg, s_bg, s_sq, s_n);
            elem_update(xv.w, tv.w, lv.w, area, s_fg, s_bg, s_sq, s_n);
        }
    }
    // wave(64) reduction
    for (int o = 32; o > 0; o >>= 1) {
        s_fg += __shfl_down(s_fg, o, 64);
        s_bg += __shfl_down(s_bg, o, 64);
        s_sq += __shfl_down(s_sq, o, 64);
        s_n  += __shfl_down(s_n,  o, 64);
    }
    // cross-wave via LDS (4 waves / 256-thread block)
    __shared__ double4 wsum[4];
    int wave = threadIdx.x >> 6;
    if ((threadIdx.x & 63) == 0)
        wsum[wave] = make_double4((double)s_fg, (double)s_bg, (double)s_sq, (double)s_n);
    __syncthreads();
    if (threadIdx.x == 0) {
        double4 b = wsum[0];
        for (int wv = 1; wv < 4; wv++) {
            b.x += wsum[wv].x; b.y += wsum[wv].y;
            b.z += wsum[wv].z; b.w += wsum[wv].w;
        }
        part[blockIdx.x] = b;
    }
}

// Single block: sum the 2048 per-block partials and finalize the loss.
__global__ void final_reduce(const double4* __restrict__ part, int nblocks,
                             float* __restrict__ out, int N) {
    double fg = 0.0, bg = 0.0, sq = 0.0, nn = 0.0;
    for (int i = threadIdx.x; i < nblocks; i += blockDim.x) {
        double4 p = part[i];
        fg += p.x; bg += p.y; sq += p.z; nn += p.w;
    }
    for (int o = 32; o > 0; o >>= 1) {
        fg += __shfl_down(fg, o, 64);
        bg += __shfl_down(bg, o, 64);
        sq += __shfl_down(sq, o, 64);
        nn += __shfl_down(nn, o, 64);
    }
    __shared__ double4 wsum[4];
    int wave = threadIdx.x >> 6;
    if ((threadIdx.x & 63) == 0) wsum[wave] = make_double4(fg, bg, sq, nn);
    __syncthreads();
    if (threadIdx.x == 0) {
        double4 b = wsum[0];
        for (int wv = 1; wv < 4; wv++) {
            b.x += wsum[wv].x; b.y += wsum[wv].y;
            b.z += wsum[wv].z; b.w += wsum[wv].w;
        }
        double mean_nz = b.z / fmax(b.w, 1.0);
        double loss = (b.x + b.y / (mean_nz + 1.0)) / (double)N;
        out[0] = (float)loss;
    }
}

// ---------------- launch ----------------

extern "C" void kernel_launch(void* const* d_in, const int* in_sizes, int n_in,
                              void* d_out, int out_size, void* d_ws, size_t ws_size,
                              hipStream_t stream) {
    const float* x = (const float*)d_in[0];   // logits
    const float* t = (const float*)d_in[1];   // binary targets
    float* out = (float*)d_out;
    const int N = in_sizes[0];                // B*H*W = 8388608

    // workspace layout: [labels: N int][area: N int][partials: RED_BLOCKS double4]
    int* L    = (int*)d_ws;
    int* area = L + N;
    double4* part = (double4*)(area + N);

    const int threads = 256;
    const int blocks  = (N + threads - 1) / threads;

    const int N4 = N / 4;                       // N is a multiple of 16
    const int init_blocks = (N4 + threads - 1) / threads;
    ccl_init<<<init_blocks, threads, 0, stream>>>((int4*)L, (int4*)area, N4);
    ccl_merge<<<blocks, threads, 0, stream>>>(t, L, N);
    ccl_flatten_count<<<blocks, threads, 0, stream>>>(t, L, area, N);
    // 2048 blocks x 256 threads, each thread 16 elements
    bce_reduce<<<RED_BLOCKS, threads, 0, stream>>>((const float4*)x, (const float4*)t,
                                                   (const int4*)L, area, part, N4);
    final_reduce<<<1, threads, 0, stream>>>(part, RED_BLOCKS, out, N);
}

// Round 4
// 201.850 us; speedup vs baseline: 3.4826x; 1.6234x over previous
//
#include <hip/hip_runtime.h>
#include <math.h>

// Problem geometry fixed by setup_inputs(): B=32, H=512, W=512.
static constexpr int IMG_W  = 512;
static constexpr int IMG_PX = 512 * 512;       // 262144
static constexpr int TILE   = 64;              // tile is 64x64
static constexpr int TPI    = IMG_W / TILE;    // 8 tiles per image dim
static constexpr int RED_BLOCKS = 2048;

// ---------------- global union-find (Playne-style BUF) ----------------

__device__ __forceinline__ int find_root_g(const int* L, int x) {
    int p = L[x];
    while (p != x) { x = p; p = L[x]; }
    return x;
}

__device__ __forceinline__ void merge_g(int* L, int a, int b) {
    while (true) {
        a = find_root_g(L, a);
        b = find_root_g(L, b);
        if (a == b) return;
        if (a < b) { int t = a; a = b; b = t; }   // a > b
        int old = atomicMin(&L[a], b);
        if (old == a) return;
        a = old;
    }
}

// ---------------- LDS union-find ----------------

__device__ __forceinline__ int find_root_l(volatile int* sl, int x) {
    int p = sl[x];
    while (p != x) { x = p; p = sl[x]; }
    return p;
}

__device__ __forceinline__ void merge_l(int* sl, int a, int b) {
    while (true) {
        a = find_root_l(sl, a);
        b = find_root_l(sl, b);
        if (a == b) return;
        if (a < b) { int t = a; a = b; b = t; }
        int old = atomicMin(&sl[a], b);
        if (old == a) return;
        a = old;
    }
}

// ---------------- kernels ----------------

// One block per 64x64 tile. Local CCL + component counts in LDS, then write
// global labels (fg -> global index of local root, bg -> self) and per-root
// counts into area[] (0 elsewhere). Fuses init+merge+flatten+count for all
// tile-interior structure.
__global__ __launch_bounds__(256) void ccl_local(const float4* __restrict__ t4,
                                                 int4* __restrict__ L4,
                                                 int4* __restrict__ A4) {
    __shared__ int sl[TILE * TILE];    // local label, -1 = background
    __shared__ int cnt[TILE * TILE];   // per-local-root pixel count

    int blk = blockIdx.x;
    int b   = blk / (TPI * TPI);
    int tid = blk % (TPI * TPI);
    int tY  = tid / TPI, tX = tid % TPI;
    int k   = threadIdx.x;
    int rb  = k >> 4;          // row within a 16-row sweep
    int c4  = (k & 15) * 4;    // column of this thread's 4-px group
    int base = b * IMG_PX + (tY * TILE) * IMG_W + tX * TILE;  // tile origin

    // phase 1: init labels + counts from targets
#pragma unroll
    for (int s = 0; s < 4; s++) {
        int row = s * 16 + rb;
        int j   = row * TILE + c4;
        int g4  = (base + row * IMG_W + c4) >> 2;
        float4 tv = t4[g4];
        sl[j]     = (tv.x != 0.f) ? j     : -1;
        sl[j + 1] = (tv.y != 0.f) ? j + 1 : -1;
        sl[j + 2] = (tv.z != 0.f) ? j + 2 : -1;
        sl[j + 3] = (tv.w != 0.f) ? j + 3 : -1;
        cnt[j] = 0; cnt[j + 1] = 0; cnt[j + 2] = 0; cnt[j + 3] = 0;
    }
    __syncthreads();

    // phase 2: merge left/up edges within the tile (LDS atomics)
#pragma unroll
    for (int s = 0; s < 4; s++) {
        int row = s * 16 + rb;
        int j   = row * TILE + c4;
#pragma unroll
        for (int m = 0; m < 4; m++) {
            int jj = j + m;
            if (sl[jj] < 0) continue;          // fg/bg status never changes
            int col = c4 + m;
            if (col > 0 && sl[jj - 1] >= 0)     merge_l(sl, jj, jj - 1);
            if (row > 0 && sl[jj - TILE] >= 0)  merge_l(sl, jj, jj - TILE);
        }
    }
    __syncthreads();

    // phase 3: flatten + count
#pragma unroll
    for (int s = 0; s < 4; s++) {
        int row = s * 16 + rb;
        int j   = row * TILE + c4;
#pragma unroll
        for (int m = 0; m < 4; m++) {
            int jj = j + m;
            if (sl[jj] < 0) continue;
            int r = find_root_l(sl, jj);
            sl[jj] = r;                        // local path compression
            atomicAdd(&cnt[r], 1);
        }
    }
    __syncthreads();

    // phase 4: coalesced write-out of L and area
#pragma unroll
    for (int s = 0; s < 4; s++) {
        int row  = s * 16 + rb;
        int j    = row * TILE + c4;
        int gElm = base + row * IMG_W + c4;
        int g4   = gElm >> 2;
        int lv[4], av[4];
#pragma unroll
        for (int m = 0; m < 4; m++) {
            int jj = j + m;
            int s0 = sl[jj];
            if (s0 < 0) { lv[m] = gElm + m; av[m] = 0; }
            else {
                lv[m] = base + (s0 >> 6) * IMG_W + (s0 & 63);  // global root idx
                av[m] = (s0 == jj) ? cnt[jj] : 0;
            }
        }
        L4[g4] = make_int4(lv[0], lv[1], lv[2], lv[3]);
        A4[g4] = make_int4(av[0], av[1], av[2], av[3]);
    }
}

// Merge across tile boundaries (global union-find on shallow trees).
__global__ void ccl_border(const float* __restrict__ t, int* __restrict__ L, int nEdges) {
    int e = blockIdx.x * blockDim.x + threadIdx.x;
    if (e >= nEdges) return;
    int perImg = (TPI - 1) * IMG_W * 2;        // 7168
    int b = e / perImg;
    int v = e % perImg;
    int g, nbr;
    if (v < (TPI - 1) * IMG_W) {               // vertical boundary columns
        int bi = v / IMG_W;                    // 0..6
        int y  = v % IMG_W;
        int x  = TILE * (bi + 1);
        g = b * IMG_PX + y * IMG_W + x;
        nbr = g - 1;
    } else {                                   // horizontal boundary rows
        int v2 = v - (TPI - 1) * IMG_W;
        int bi = v2 / IMG_W;
        int x  = v2 % IMG_W;
        int y  = TILE * (bi + 1);
        g = b * IMG_PX + y * IMG_W + x;
        nbr = g - IMG_W;
    }
    if (t[g] != 0.f && t[nbr] != 0.f) merge_g(L, g, nbr);
}

// Move counts from displaced local roots to their final roots; compress.
__global__ void area_fixup(int* __restrict__ L, int* __restrict__ area,
                           const int4* __restrict__ A4, int N4) {
    int i = blockIdx.x * blockDim.x + threadIdx.x;
    if (i >= N4) return;
    int4 a = A4[i];
    int g0 = i * 4;
#pragma unroll
    for (int m = 0; m < 4; m++) {
        int av = (m == 0) ? a.x : (m == 1) ? a.y : (m == 2) ? a.z : a.w;
        if (av > 0) {
            int g = g0 + m;
            int r = find_root_g(L, g);
            if (r != g) { atomicAdd(&area[r], av); L[g] = r; }
        }
    }
}

// branchless per-element update. Per-pixel label may need a short chase
// (local root -> final root, <=2 hops; bg self-loops and L1-hits).
__device__ __forceinline__ void elem_update(float x, float t, int l,
                                            const int* __restrict__ L,
                                            const int* __restrict__ area,
                                            float& s_fg, float& s_bg,
                                            float& s_sq, float& s_n) {
    int p = L[l];
    while (p != l) { l = p; p = L[l]; }
    float w   = sqrtf((float)area[l]);
    float bce = fmaxf(x, 0.f) - x * t + log1pf(expf(-fabsf(x)));
    float bt  = t * bce;
    s_fg += bt / (w + 1.f);
    s_bg += bce - bt;
    s_sq += w;
    s_n  += t;
}

__global__ void bce_reduce(const float4* __restrict__ x4, const float4* __restrict__ t4,
                           const int4* __restrict__ L4, const int* __restrict__ L,
                           const int* __restrict__ area,
                           double4* __restrict__ part, int N4) {
    float s_fg = 0.f, s_bg = 0.f, s_sq = 0.f, s_n = 0.f;
    int tid    = blockIdx.x * blockDim.x + threadIdx.x;
    int stride = gridDim.x * blockDim.x;
#pragma unroll
    for (int k = 0; k < 4; k++) {
        int i = tid + k * stride;
        if (i < N4) {
            float4 xv = x4[i];
            float4 tv = t4[i];
            int4   lv = L4[i];
            elem_update(xv.x, tv.x, lv.x, L, area, s_fg, s_bg, s_sq, s_n);
            elem_update(xv.y, tv.y, lv.y, L, area, s_fg, s_bg, s_sq, s_n);
            elem_update(xv.z, tv.z, lv.z, L, area, s_fg, s_bg, s_sq, s_n);
            elem_update(xv.w, tv.w, lv.w, L, area, s_fg, s_bg, s_sq, s_n);
        }
    }
    // wave(64) reduction
    for (int o = 32; o > 0; o >>= 1) {
        s_fg += __shfl_down(s_fg, o, 64);
        s_bg += __shfl_down(s_bg, o, 64);
        s_sq += __shfl_down(s_sq, o, 64);
        s_n  += __shfl_down(s_n,  o, 64);
    }
    __shared__ double4 wsum[4];
    int wave = threadIdx.x >> 6;
    if ((threadIdx.x & 63) == 0)
        wsum[wave] = make_double4((double)s_fg, (double)s_bg, (double)s_sq, (double)s_n);
    __syncthreads();
    if (threadIdx.x == 0) {
        double4 bsum = wsum[0];
        for (int wv = 1; wv < 4; wv++) {
            bsum.x += wsum[wv].x; bsum.y += wsum[wv].y;
            bsum.z += wsum[wv].z; bsum.w += wsum[wv].w;
        }
        part[blockIdx.x] = bsum;
    }
}

__global__ void final_reduce(const double4* __restrict__ part, int nblocks,
                             float* __restrict__ out, int N) {
    double fg = 0.0, bg = 0.0, sq = 0.0, nn = 0.0;
    for (int i = threadIdx.x; i < nblocks; i += blockDim.x) {
        double4 p = part[i];
        fg += p.x; bg += p.y; sq += p.z; nn += p.w;
    }
    for (int o = 32; o > 0; o >>= 1) {
        fg += __shfl_down(fg, o, 64);
        bg += __shfl_down(bg, o, 64);
        sq += __shfl_down(sq, o, 64);
        nn += __shfl_down(nn, o, 64);
    }
    __shared__ double4 wsum[4];
    int wave = threadIdx.x >> 6;
    if ((threadIdx.x & 63) == 0) wsum[wave] = make_double4(fg, bg, sq, nn);
    __syncthreads();
    if (threadIdx.x == 0) {
        double4 b = wsum[0];
        for (int wv = 1; wv < 4; wv++) {
            b.x += wsum[wv].x; b.y += wsum[wv].y;
            b.z += wsum[wv].z; b.w += wsum[wv].w;
        }
        double mean_nz = b.z / fmax(b.w, 1.0);
        double loss = (b.x + b.y / (mean_nz + 1.0)) / (double)N;
        out[0] = (float)loss;
    }
}

// ---------------- launch ----------------

extern "C" void kernel_launch(void* const* d_in, const int* in_sizes, int n_in,
                              void* d_out, int out_size, void* d_ws, size_t ws_size,
                              hipStream_t stream) {
    const float* x = (const float*)d_in[0];   // logits
    const float* t = (const float*)d_in[1];   // binary targets
    float* out = (float*)d_out;
    const int N = in_sizes[0];                // B*H*W = 8388608
    const int B = N / IMG_PX;                 // 32

    // workspace layout: [labels: N int][area: N int][partials: RED_BLOCKS double4]
    int* L    = (int*)d_ws;
    int* area = L + N;
    double4* part = (double4*)(area + N);

    const int threads = 256;
    const int N4 = N / 4;

    // 1. local CCL: one block per 64x64 tile
    ccl_local<<<B * TPI * TPI, threads, 0, stream>>>((const float4*)t, (int4*)L, (int4*)area);
    // 2. cross-tile merges
    const int nEdges = B * (TPI - 1) * IMG_W * 2;   // 229376
    ccl_border<<<(nEdges + threads - 1) / threads, threads, 0, stream>>>(t, L, nEdges);
    // 3. migrate counts of displaced roots
    area_fixup<<<(N4 + threads - 1) / threads, threads, 0, stream>>>(L, area, (const int4*)area, N4);
    // 4. weighted BCE reduction (per-block partials, no contended atomics)
    bce_reduce<<<RED_BLOCKS, threads, 0, stream>>>((const float4*)x, (const float4*)t,
                                                   (const int4*)L, L, area, part, N4);
    // 5. finalize
    final_reduce<<<1, threads, 0, stream>>>(part, RED_BLOCKS, out, N);
}